// Round 2
// baseline (1348.303 us; speedup 1.0000x reference)
//
#include <hip/hip_runtime.h>
#include <hip/hip_bf16.h>
#include <math.h>

#define DEV static __device__ __forceinline__

typedef __bf16 bf16;
typedef __bf16 bf16x8 __attribute__((ext_vector_type(8)));
typedef __bf16 bf16x4 __attribute__((ext_vector_type(4)));
typedef float f32x4 __attribute__((ext_vector_type(4)));

#define B_ 8
#define N_ 4096
#define DD 1024
#define KSLOTS 64
#define EPS_ 1e-5f

enum { EPI_F32=0, EPI_BF16=1, EPI_BIAS_BF16=2, EPI_BIAS_GELU_BF16=3, EPI_BIAS_RES_F32=4, EPI_SCALE_BF16=5 };

typedef __attribute__((address_space(1))) void gvoid;
typedef __attribute__((address_space(3))) void lvoid;

DEV void gload16(const void* g, void* l) {
    __builtin_amdgcn_global_load_lds((gvoid*)g, (lvoid*)l, 16, 0, 0);
}

// C[M,N] = A[M,K] * Bt[N,K]^T ; A,Bt bf16, acc fp32.
// 256 threads = 4 waves; each wave computes a 64x64 sub-tile (4x4 frags of 16x16).
template<int BM, int BN, int EPI>
__global__ __launch_bounds__(256) void gemm_bt(
    const bf16* __restrict__ A, const bf16* __restrict__ Bt, void* __restrict__ Cv,
    const float* __restrict__ bias, const float* __restrict__ res,
    int M, int N, int Kd, long sA, long sB, long sC, float scale)
{
    constexpr int WGM = BM / 64;
    constexpr int WGN = 4 / WGM;
    static_assert(WGM * 64 == BM, "BM");
    static_assert(WGN * 64 == BN, "BN");

    __shared__ __align__(16) short lA[BM * 32];
    __shared__ __align__(16) short lB[BN * 32];

    const int tid  = threadIdx.x;
    const int lane = tid & 63;
    const int wave = tid >> 6;
    const int wm = wave / WGN;
    const int wn = wave % WGN;
    const int lr = lane & 15;
    const int lk = lane >> 4;
    const long z = blockIdx.z;

    const bf16* ga = A  + z * sA + (long)blockIdx.y * BM * Kd;
    const bf16* gb = Bt + z * sB + (long)blockIdx.x * BN * Kd;

    f32x4 acc[4][4] = {};

    for (int k0 = 0; k0 < Kd; k0 += 32) {
        #pragma unroll
        for (int j = 0; j < BM / 64; ++j) {
            int c = j * 256 + tid;
            gload16(ga + (long)(c >> 2) * Kd + k0 + (c & 3) * 8,
                    lA + (j * 256 + wave * 64) * 8);
        }
        #pragma unroll
        for (int j = 0; j < BN / 64; ++j) {
            int c = j * 256 + tid;
            gload16(gb + (long)(c >> 2) * Kd + k0 + (c & 3) * 8,
                    lB + (j * 256 + wave * 64) * 8);
        }
        __syncthreads();

        bf16x8 af[4], bfr[4];
        #pragma unroll
        for (int i = 0; i < 4; ++i)
            af[i] = *(const bf16x8*)&lA[(wm * 64 + i * 16 + lr) * 32 + lk * 8];
        #pragma unroll
        for (int i = 0; i < 4; ++i)
            bfr[i] = *(const bf16x8*)&lB[(wn * 64 + i * 16 + lr) * 32 + lk * 8];

        #pragma unroll
        for (int i = 0; i < 4; ++i)
            #pragma unroll
            for (int j = 0; j < 4; ++j)
                acc[i][j] = __builtin_amdgcn_mfma_f32_16x16x32_bf16(af[i], bfr[j], acc[i][j], 0, 0, 0);
        __syncthreads();
    }

    const int rowb = blockIdx.y * BM + wm * 64;
    const int colb = blockIdx.x * BN + wn * 64;
    const long cb = z * sC;

    #pragma unroll
    for (int i = 0; i < 4; ++i) {
        #pragma unroll
        for (int j = 0; j < 4; ++j) {
            const int col = colb + j * 16 + lr;
            float bv = 0.f;
            if (EPI == EPI_BIAS_BF16 || EPI == EPI_BIAS_GELU_BF16 || EPI == EPI_BIAS_RES_F32)
                bv = bias[col];
            #pragma unroll
            for (int r = 0; r < 4; ++r) {
                const int row = rowb + i * 16 + lk * 4 + r;
                const long off = cb + (long)row * N + col;
                float v = acc[i][j][r];
                if (EPI == EPI_F32) {
                    ((float*)Cv)[off] = v;
                } else if (EPI == EPI_BF16) {
                    ((bf16*)Cv)[off] = (bf16)v;
                } else if (EPI == EPI_BIAS_BF16) {
                    ((bf16*)Cv)[off] = (bf16)(v + bv);
                } else if (EPI == EPI_SCALE_BF16) {
                    ((bf16*)Cv)[off] = (bf16)(v * scale);
                } else if (EPI == EPI_BIAS_GELU_BF16) {
                    float t = v + bv;
                    t = 0.5f * t * (1.f + erff(t * 0.70710678118f));
                    ((bf16*)Cv)[off] = (bf16)t;
                } else { // EPI_BIAS_RES_F32
                    ((float*)Cv)[off] = v + bv + res[off];
                }
            }
        }
    }
}

// LayerNorm over rows of length 1024; writes bf16 out, optionally also f32 copy
// (used for slots: the reference REASSIGNS slots to LN(slots), and the residual
//  adds mlp to the NORMALIZED slots).
template<typename TIN, bool WRITE_F32>
__global__ __launch_bounds__(256) void ln_rows(const TIN* __restrict__ in, bf16* __restrict__ out,
                                               float* __restrict__ outf,
                                               const float* __restrict__ g, const float* __restrict__ b)
{
    const int row = blockIdx.x;
    const int tid = threadIdx.x;
    const long base = (long)row * 1024 + tid * 4;
    float x[4];
    if constexpr (sizeof(TIN) == 2) {
        bf16x4 v = *(const bf16x4*)(in + base);
        #pragma unroll
        for (int i = 0; i < 4; ++i) x[i] = (float)v[i];
    } else {
        float4 v = *(const float4*)(in + base);
        x[0] = v.x; x[1] = v.y; x[2] = v.z; x[3] = v.w;
    }
    float s = 0.f, s2 = 0.f;
    #pragma unroll
    for (int i = 0; i < 4; ++i) { s += x[i]; s2 += x[i] * x[i]; }
    #pragma unroll
    for (int o = 32; o; o >>= 1) { s += __shfl_down(s, o); s2 += __shfl_down(s2, o); }
    __shared__ float red[2][4];
    const int lane = tid & 63, wv = tid >> 6;
    if (!lane) { red[0][wv] = s; red[1][wv] = s2; }
    __syncthreads();
    s  = red[0][0] + red[0][1] + red[0][2] + red[0][3];
    s2 = red[1][0] + red[1][1] + red[1][2] + red[1][3];
    const float mu = s * (1.f / 1024.f);
    const float var = s2 * (1.f / 1024.f) - mu * mu;
    const float rstd = rsqrtf(var + EPS_);
    const int c0 = tid * 4;
    bf16x4 o;
    float of[4];
    #pragma unroll
    for (int i = 0; i < 4; ++i) {
        float y = (x[i] - mu) * rstd * g[c0 + i] + b[c0 + i];
        o[i] = (bf16)y;
        of[i] = y;
    }
    *(bf16x4*)(out + base) = o;
    if constexpr (WRITE_F32) {
        float4 v4; v4.x = of[0]; v4.y = of[1]; v4.z = of[2]; v4.w = of[3];
        *(float4*)(outf + base) = v4;
    }
}

// softmax over the K=64 slots axis of logits [B][64][N_]; writes bf16 attn.
__global__ __launch_bounds__(256) void softmax_k(const float* __restrict__ lg, bf16* __restrict__ attn)
{
    const int n = blockIdx.x * 256 + threadIdx.x;
    const long base = (long)blockIdx.y * KSLOTS * N_ + n;
    float v[KSLOTS];
    float mx = -1e30f;
    #pragma unroll
    for (int k = 0; k < KSLOTS; ++k) { v[k] = lg[base + (long)k * N_]; mx = fmaxf(mx, v[k]); }
    float s = 0.f;
    #pragma unroll
    for (int k = 0; k < KSLOTS; ++k) { v[k] = expf(v[k] - mx); s += v[k]; }
    const float inv = 1.f / s;
    #pragma unroll
    for (int k = 0; k < KSLOTS; ++k) attn[base + (long)k * N_] = (bf16)(v[k] * inv);
}

// out[c][r] = (bf16) in[r][c]; in is [R][C] fp32.
__global__ __launch_bounds__(256) void transpose_w(const float* __restrict__ in, bf16* __restrict__ out,
                                                   int R, int C)
{
    __shared__ float t[32][33];
    const int tx = threadIdx.x, ty = threadIdx.y;
    const int c0 = blockIdx.x * 32, r0 = blockIdx.y * 32;
    #pragma unroll
    for (int j = 0; j < 4; ++j)
        t[ty + j * 8][tx] = in[(long)(r0 + ty + j * 8) * C + c0 + tx];
    __syncthreads();
    #pragma unroll
    for (int j = 0; j < 4; ++j)
        out[(long)(c0 + ty + j * 8) * R + r0 + tx] = (bf16)t[tx][ty + j * 8];
}

__global__ __launch_bounds__(256) void cvt_to_bf16(const float* __restrict__ in, bf16* __restrict__ out, long n)
{
    const long i = ((long)blockIdx.x * 256 + threadIdx.x) * 4;
    if (i >= n) return;
    float4 f = *(const float4*)(in + i);
    bf16x4 o; o[0] = (bf16)f.x; o[1] = (bf16)f.y; o[2] = (bf16)f.z; o[3] = (bf16)f.w;
    *(bf16x4*)(out + i) = o;
}

__global__ __launch_bounds__(256) void bcast_slots(const float* __restrict__ seed, float* __restrict__ slots)
{
    const int i = blockIdx.x * 256 + threadIdx.x;
    slots[i] = seed[i & 65535];
}

extern "C" void kernel_launch(void* const* d_in, const int* in_sizes, int n_in,
                              void* d_out, int out_size, void* d_ws, size_t ws_size,
                              hipStream_t stream) {
    const float* inputs     = (const float*)d_in[0];
    const float* W_in       = (const float*)d_in[1];
    const float* b_in       = (const float*)d_in[2];
    const float* slots_seed = (const float*)d_in[3];
    const float* ln_in_g    = (const float*)d_in[4];
    const float* ln_in_b    = (const float*)d_in[5];
    const float* ln_sl_g    = (const float*)d_in[6];
    const float* ln_sl_b    = (const float*)d_in[7];
    const float* ln_mlp_g   = (const float*)d_in[8];
    const float* ln_mlp_b   = (const float*)d_in[9];
    const float* Wq         = (const float*)d_in[10];
    const float* Wk         = (const float*)d_in[11];
    const float* Wv         = (const float*)d_in[12];
    const float* W1         = (const float*)d_in[13];
    const float* b1         = (const float*)d_in[14];
    const float* W2         = (const float*)d_in[15];
    const float* b2         = (const float*)d_in[16];

    char* ws = (char*)d_ws;
    const long MB = 1 << 20;
    bf16* WT_IN = (bf16*)(ws + 0 * MB);     // [1024][1024]
    bf16* WQT   = (bf16*)(ws + 2 * MB);
    bf16* WKT   = (bf16*)(ws + 4 * MB);
    bf16* WVT   = (bf16*)(ws + 6 * MB);
    bf16* W1T   = (bf16*)(ws + 8 * MB);     // [2048][1024]
    bf16* W2T   = (bf16*)(ws + 12 * MB);    // [1024][2048]
    float* SLOTS = (float*)(ws + 16 * MB);  // [8*64][1024]
    bf16* SLN   = (bf16*)(ws + 18 * MB);    // [512][1024] (slots_ln, then h)
    bf16* Q     = (bf16*)(ws + 19 * MB);    // [8*64][1024]
    float* LOGITS = (float*)(ws + 20 * MB); // [8][64][4096]
    bf16* ATTN  = (bf16*)(ws + 28 * MB);    // [8][64][4096]
    float* UPD  = (float*)(ws + 32 * MB);   // [8*64][1024]
    bf16* MLP1  = (bf16*)(ws + 34 * MB);    // [512][2048]
    bf16* X     = (bf16*)(ws + 36 * MB);    // [32768][1024]
    bf16* INP_BF = (bf16*)(ws + 100 * MB);  // [32768][1024] (k aliases after use)
    bf16* K_BF  = INP_BF;
    bf16* XPRE  = (bf16*)(ws + 164 * MB);   // [32768][1024] (vT aliases after use)
    bf16* VT    = XPRE;                     // [8][1024][4096]

    dim3 blk(256);
    dim3 tblk(32, 8);

    transpose_w<<<dim3(32, 32), tblk, 0, stream>>>(W_in, WT_IN, 1024, 1024);
    transpose_w<<<dim3(32, 32), tblk, 0, stream>>>(Wq,   WQT,   1024, 1024);
    transpose_w<<<dim3(32, 32), tblk, 0, stream>>>(Wk,   WKT,   1024, 1024);
    transpose_w<<<dim3(32, 32), tblk, 0, stream>>>(Wv,   WVT,   1024, 1024);
    transpose_w<<<dim3(64, 32), tblk, 0, stream>>>(W1,   W1T,   1024, 2048);
    transpose_w<<<dim3(32, 64), tblk, 0, stream>>>(W2,   W2T,   2048, 1024);

    cvt_to_bf16<<<32768, blk, 0, stream>>>(inputs, INP_BF, (long)32768 * 1024);
    bcast_slots<<<2048, blk, 0, stream>>>(slots_seed, SLOTS);

    // xpre = inputs @ W_in + b_in  (bf16)
    gemm_bt<128, 128, EPI_BIAS_BF16><<<dim3(8, 256, 1), blk, 0, stream>>>(
        INP_BF, WT_IN, XPRE, b_in, nullptr, 32768, 1024, 1024, 0, 0, 0, 1.f);
    // x = LN(xpre)
    ln_rows<bf16, false><<<32768, blk, 0, stream>>>(XPRE, X, nullptr, ln_in_g, ln_in_b);
    // k = x @ Wk  (bf16) — overwrites INP_BF region (dead)
    gemm_bt<128, 128, EPI_BF16><<<dim3(8, 256, 1), blk, 0, stream>>>(
        X, WKT, K_BF, nullptr, nullptr, 32768, 1024, 1024, 0, 0, 0, 1.f);
    // vT_b = Wv^T @ x_b^T  → [8][1024][4096] bf16 — overwrites XPRE region (dead)
    gemm_bt<128, 128, EPI_BF16><<<dim3(32, 8, 8), blk, 0, stream>>>(
        WVT, X, VT, nullptr, nullptr, 1024, 4096, 1024,
        0, (long)4096 * 1024, (long)1024 * 4096, 1.f);

    for (int it = 0; it < 3; ++it) {
        // slots = LN(slots)  — reference REASSIGNS slots; keep f32 copy in SLOTS
        // (in-place) and bf16 copy in SLN for the q GEMM.
        ln_rows<float, true><<<512, blk, 0, stream>>>(SLOTS, SLN, SLOTS, ln_sl_g, ln_sl_b);
        // q = slots_ln @ Wq * D^-0.5  (bf16)
        gemm_bt<128, 128, EPI_SCALE_BF16><<<dim3(8, 4, 1), blk, 0, stream>>>(
            SLN, WQT, Q, nullptr, nullptr, 512, 1024, 1024, 0, 0, 0, 0.03125f);
        // logits_b = q_b @ k_b^T  (f32)
        gemm_bt<64, 256, EPI_F32><<<dim3(16, 1, 8), blk, 0, stream>>>(
            Q, K_BF, LOGITS, nullptr, nullptr, 64, 4096, 1024,
            (long)64 * 1024, (long)4096 * 1024, (long)64 * 4096, 1.f);
        softmax_k<<<dim3(16, 8), blk, 0, stream>>>(LOGITS, ATTN);
        // updates_b = attn_b @ v_b  (f32) via Bt = vT_b
        gemm_bt<64, 256, EPI_F32><<<dim3(4, 1, 8), blk, 0, stream>>>(
            ATTN, VT, UPD, nullptr, nullptr, 64, 1024, 4096,
            (long)64 * 4096, (long)1024 * 4096, (long)64 * 1024, 1.f);
        ln_rows<float, false><<<512, blk, 0, stream>>>(UPD, SLN, nullptr, ln_mlp_g, ln_mlp_b);
        // mlp1 = gelu(h @ W1 + b1)  (bf16)
        gemm_bt<128, 128, EPI_BIAS_GELU_BF16><<<dim3(16, 4, 1), blk, 0, stream>>>(
            SLN, W1T, MLP1, b1, nullptr, 512, 2048, 1024, 0, 0, 0, 1.f);
        // slots = slots_ln + mlp1 @ W2 + b2  (f32, in-place residual on LN'd slots)
        gemm_bt<128, 128, EPI_BIAS_RES_F32><<<dim3(8, 4, 1), blk, 0, stream>>>(
            MLP1, W2T, SLOTS, b2, SLOTS, 512, 1024, 2048, 0, 0, 0, 1.f);
    }

    hipMemcpyAsync(d_out, SLOTS, (size_t)512 * 1024 * 4, hipMemcpyDeviceToDevice, stream);
}

// Round 4
// 983.874 us; speedup vs baseline: 1.3704x; 1.3704x over previous
//
#include <hip/hip_runtime.h>
#include <hip/hip_bf16.h>
#include <math.h>

#define DEV static __device__ __forceinline__

typedef __bf16 bf16;
typedef __bf16 bf16x8 __attribute__((ext_vector_type(8)));
typedef __bf16 bf16x4 __attribute__((ext_vector_type(4)));
typedef float f32x4 __attribute__((ext_vector_type(4)));

#define B_ 8
#define N_ 4096
#define DD 1024
#define KSLOTS 64
#define EPS_ 1e-5f

enum { EPI_F32=0, EPI_BF16=1, EPI_BIAS_BF16=2, EPI_BIAS_GELU_BF16=3, EPI_SCALE_BF16=5 };

typedef __attribute__((address_space(1))) void gvoid;
typedef __attribute__((address_space(3))) void lvoid;

DEV void gload16(const void* g, void* l) {
    __builtin_amdgcn_global_load_lds((gvoid*)g, (lvoid*)l, 16, 0, 0);
}

// C[M,N] = A[M,K] * Bt[N,K]^T ; A,Bt bf16, acc fp32. 256 threads = 4 waves.
// Wave grid WM x WN (WM*WN==4); per-wave frag counts AM x AN of 16x16.
// KSPLIT>1: writes f32 partials at Cv + ks*pStride (EPI must be EPI_F32).
// SWZ: 0 none; 1 = XCD swizzle, x-inner; 2 = XCD swizzle, y-inner.
template<int BM, int BN, int WM, int WN, int EPI, int KSPLIT, int SWZ>
__global__ __launch_bounds__(256) void gemm_bt(
    const bf16* __restrict__ A, const bf16* __restrict__ Bt, void* __restrict__ Cv,
    const float* __restrict__ bias,
    int N, int Kd, long sA, long sB, long sC, float scale,
    int gx, int gy, long pStride)
{
    constexpr int AM = BM / (WM * 16);
    constexpr int AN = BN / (WN * 16);
    static_assert(WM * WN == 4, "waves");

    __shared__ __align__(16) short lA[BM * 32];
    __shared__ __align__(16) short lB[BN * 32];

    int lin = blockIdx.x;
    if (SWZ) {
        int cpx = gridDim.x >> 3;           // grid % 8 == 0 guaranteed by caller
        lin = (lin & 7) * cpx + (lin >> 3);
    }
    int bx, by, bzk;
    if (SWZ == 2) { by = lin % gy; int t = lin / gy; bx = t % gx; bzk = t / gx; }
    else          { bx = lin % gx; int t = lin / gx; by = t % gy; bzk = t / gy; }
    const int b  = bzk / KSPLIT;
    const int ks = bzk % KSPLIT;
    const int kLen = Kd / KSPLIT;
    const int kBeg = ks * kLen;

    const int tid  = threadIdx.x;
    const int lane = tid & 63;
    const int wave = tid >> 6;
    const int wm = wave / WN;
    const int wn = wave % WN;
    const int lr = lane & 15;
    const int lk = lane >> 4;

    const bf16* ga = A  + (long)b * sA + (long)by * BM * Kd;
    const bf16* gb = Bt + (long)b * sB + (long)bx * BN * Kd;

    f32x4 acc[AM][AN] = {};

    for (int k0 = kBeg; k0 < kBeg + kLen; k0 += 32) {
        #pragma unroll
        for (int j = 0; j < BM / 64; ++j) {
            int c = j * 256 + tid;
            gload16(ga + (long)(c >> 2) * Kd + k0 + (c & 3) * 8,
                    lA + (j * 256 + wave * 64) * 8);
        }
        #pragma unroll
        for (int j = 0; j < BN / 64; ++j) {
            int c = j * 256 + tid;
            gload16(gb + (long)(c >> 2) * Kd + k0 + (c & 3) * 8,
                    lB + (j * 256 + wave * 64) * 8);
        }
        __syncthreads();

        bf16x8 af[AM], bfr[AN];
        #pragma unroll
        for (int i = 0; i < AM; ++i)
            af[i] = *(const bf16x8*)&lA[(wm * AM * 16 + i * 16 + lr) * 32 + lk * 8];
        #pragma unroll
        for (int j = 0; j < AN; ++j)
            bfr[j] = *(const bf16x8*)&lB[(wn * AN * 16 + j * 16 + lr) * 32 + lk * 8];

        #pragma unroll
        for (int i = 0; i < AM; ++i)
            #pragma unroll
            for (int j = 0; j < AN; ++j)
                acc[i][j] = __builtin_amdgcn_mfma_f32_16x16x32_bf16(af[i], bfr[j], acc[i][j], 0, 0, 0);
        __syncthreads();
    }

    const int rowb = by * BM + wm * AM * 16;
    const int colb = bx * BN + wn * AN * 16;

    #pragma unroll
    for (int i = 0; i < AM; ++i) {
        #pragma unroll
        for (int j = 0; j < AN; ++j) {
            const int col = colb + j * 16 + lr;
            float bv = 0.f;
            if (EPI == EPI_BIAS_BF16 || EPI == EPI_BIAS_GELU_BF16)
                bv = bias[col];
            #pragma unroll
            for (int r = 0; r < 4; ++r) {
                const int row = rowb + i * 16 + lk * 4 + r;
                float v = acc[i][j][r];
                if (KSPLIT > 1) {
                    float* P = (float*)Cv + (long)ks * pStride;
                    P[(long)b * sC + (long)row * N + col] = v;
                } else {
                    const long off = (long)b * sC + (long)row * N + col;
                    if (EPI == EPI_F32) {
                        ((float*)Cv)[off] = v;
                    } else if (EPI == EPI_BF16) {
                        ((bf16*)Cv)[off] = (bf16)v;
                    } else if (EPI == EPI_BIAS_BF16) {
                        ((bf16*)Cv)[off] = (bf16)(v + bv);
                    } else if (EPI == EPI_SCALE_BF16) {
                        ((bf16*)Cv)[off] = (bf16)(v * scale);
                    } else if (EPI == EPI_BIAS_GELU_BF16) {
                        float t = v + bv;
                        t = 0.5f * t * (1.f + erff(t * 0.70710678118f));
                        ((bf16*)Cv)[off] = (bf16)t;
                    }
                }
            }
        }
    }
}

// Fused logits + column-softmax (over the 64 slots) -> attn bf16.
// BM=64 (all slots), BN=128, WM=1, WN=4. grid = 32 n-tiles * 8 batches.
__global__ __launch_bounds__(256) void qk_softmax(
    const bf16* __restrict__ Q, const bf16* __restrict__ Kb, bf16* __restrict__ attn)
{
    __shared__ __align__(16) short lA[64 * 32];
    __shared__ __align__(16) short lB[128 * 32];

    const int bx = blockIdx.x & 31;
    const int z  = blockIdx.x >> 5;
    const int tid  = threadIdx.x;
    const int lane = tid & 63;
    const int wave = tid >> 6;   // = wn
    const int lr = lane & 15;
    const int lk = lane >> 4;

    const bf16* ga = Q  + (long)z * (KSLOTS * DD);
    const bf16* gb = Kb + (long)z * (N_ * DD) + (long)bx * 128 * DD;

    f32x4 acc[4][2] = {};

    for (int k0 = 0; k0 < DD; k0 += 32) {
        {
            int c = tid;
            gload16(ga + (long)(c >> 2) * DD + k0 + (c & 3) * 8, lA + (wave * 64) * 8);
        }
        #pragma unroll
        for (int j = 0; j < 2; ++j) {
            int c = j * 256 + tid;
            gload16(gb + (long)(c >> 2) * DD + k0 + (c & 3) * 8,
                    lB + (j * 256 + wave * 64) * 8);
        }
        __syncthreads();

        bf16x8 af[4], bfr[2];
        #pragma unroll
        for (int i = 0; i < 4; ++i)
            af[i] = *(const bf16x8*)&lA[(i * 16 + lr) * 32 + lk * 8];
        #pragma unroll
        for (int j = 0; j < 2; ++j)
            bfr[j] = *(const bf16x8*)&lB[(wave * 32 + j * 16 + lr) * 32 + lk * 8];

        #pragma unroll
        for (int i = 0; i < 4; ++i)
            #pragma unroll
            for (int j = 0; j < 2; ++j)
                acc[i][j] = __builtin_amdgcn_mfma_f32_16x16x32_bf16(af[i], bfr[j], acc[i][j], 0, 0, 0);
        __syncthreads();
    }

    bf16* ob = attn + (long)z * (KSLOTS * N_);
    #pragma unroll
    for (int j = 0; j < 2; ++j) {
        const int col = bx * 128 + wave * 32 + j * 16 + lr;
        float m = -1e30f;
        #pragma unroll
        for (int i = 0; i < 4; ++i)
            #pragma unroll
            for (int r = 0; r < 4; ++r) m = fmaxf(m, acc[i][j][r]);
        m = fmaxf(m, __shfl_xor(m, 16));
        m = fmaxf(m, __shfl_xor(m, 32));
        float e[4][4], s = 0.f;
        #pragma unroll
        for (int i = 0; i < 4; ++i)
            #pragma unroll
            for (int r = 0; r < 4; ++r) { e[i][r] = __expf(acc[i][j][r] - m); s += e[i][r]; }
        s += __shfl_xor(s, 16);
        s += __shfl_xor(s, 32);
        const float inv = 1.f / s;
        #pragma unroll
        for (int i = 0; i < 4; ++i)
            #pragma unroll
            for (int r = 0; r < 4; ++r)
                ob[(long)(i * 16 + lk * 4 + r) * N_ + col] = (bf16)(e[i][r] * inv);
    }
}

// LayerNorm over rows of length 1024.
// NPART>1: input = NPART f32 partials (summed). ADD_BR: += bias[col] + res[row] first.
// WRITE_F32: also write f32 result to outf (may alias res).
template<int NPART, bool ADD_BR, typename TIN, bool WRITE_F32>
__global__ __launch_bounds__(256) void ln_rows(const TIN* __restrict__ in, bf16* __restrict__ out,
                                               float* outf, const float* __restrict__ g,
                                               const float* __restrict__ b,
                                               const float* __restrict__ bias, const float* res,
                                               long pStride)
{
    const int row = blockIdx.x;
    const int tid = threadIdx.x;
    const long base = (long)row * 1024 + tid * 4;
    float x[4];
    if constexpr (sizeof(TIN) == 2) {
        bf16x4 v = *(const bf16x4*)(in + base);
        #pragma unroll
        for (int i = 0; i < 4; ++i) x[i] = (float)v[i];
    } else {
        float4 v = *(const float4*)((const float*)in + base);
        x[0] = v.x; x[1] = v.y; x[2] = v.z; x[3] = v.w;
        #pragma unroll
        for (int p = 1; p < NPART; ++p) {
            float4 w = *(const float4*)((const float*)in + p * pStride + base);
            x[0] += w.x; x[1] += w.y; x[2] += w.z; x[3] += w.w;
        }
    }
    const int c0 = tid * 4;
    if constexpr (ADD_BR) {
        float4 rv = *(const float4*)(res + base);
        x[0] += bias[c0 + 0] + rv.x; x[1] += bias[c0 + 1] + rv.y;
        x[2] += bias[c0 + 2] + rv.z; x[3] += bias[c0 + 3] + rv.w;
    }
    float s = 0.f, s2 = 0.f;
    #pragma unroll
    for (int i = 0; i < 4; ++i) { s += x[i]; s2 += x[i] * x[i]; }
    #pragma unroll
    for (int o = 32; o; o >>= 1) { s += __shfl_down(s, o); s2 += __shfl_down(s2, o); }
    __shared__ float red[2][4];
    const int lane = tid & 63, wv = tid >> 6;
    if (!lane) { red[0][wv] = s; red[1][wv] = s2; }
    __syncthreads();
    s  = red[0][0] + red[0][1] + red[0][2] + red[0][3];
    s2 = red[1][0] + red[1][1] + red[1][2] + red[1][3];
    const float mu = s * (1.f / 1024.f);
    const float var = s2 * (1.f / 1024.f) - mu * mu;
    const float rstd = rsqrtf(var + EPS_);
    bf16x4 o;
    float of[4];
    #pragma unroll
    for (int i = 0; i < 4; ++i) {
        float y = (x[i] - mu) * rstd * g[c0 + i] + b[c0 + i];
        o[i] = (bf16)y; of[i] = y;
    }
    *(bf16x4*)(out + base) = o;
    if constexpr (WRITE_F32) {
        float4 v4; v4.x = of[0]; v4.y = of[1]; v4.z = of[2]; v4.w = of[3];
        *(float4*)(outf + base) = v4;
    }
}

// final slots = p0 + p1 + b2 + slots_ln  -> d_out (f32)
__global__ __launch_bounds__(256) void finalize(const float* __restrict__ P, const float* __restrict__ bias,
                                                const float* __restrict__ res, float* __restrict__ out)
{
    const int row = blockIdx.x;
    const int tid = threadIdx.x;
    const long base = (long)row * 1024 + tid * 4;
    float4 a = *(const float4*)(P + base);
    float4 c = *(const float4*)(P + 524288 + base);
    float4 rv = *(const float4*)(res + base);
    const int c0 = tid * 4;
    float4 o;
    o.x = a.x + c.x + bias[c0 + 0] + rv.x;
    o.y = a.y + c.y + bias[c0 + 1] + rv.y;
    o.z = a.z + c.z + bias[c0 + 2] + rv.z;
    o.w = a.w + c.w + bias[c0 + 3] + rv.w;
    *(float4*)(out + base) = o;
}

// out[c][r] = (bf16) in[r][c]; in is [R][C] fp32.
__global__ __launch_bounds__(256) void transpose_w(const float* __restrict__ in, bf16* __restrict__ out,
                                                   int R, int C)
{
    __shared__ float t[32][33];
    const int tx = threadIdx.x, ty = threadIdx.y;
    const int c0 = blockIdx.x * 32, r0 = blockIdx.y * 32;
    #pragma unroll
    for (int j = 0; j < 4; ++j)
        t[ty + j * 8][tx] = in[(long)(r0 + ty + j * 8) * C + c0 + tx];
    __syncthreads();
    #pragma unroll
    for (int j = 0; j < 4; ++j)
        out[(long)(c0 + ty + j * 8) * R + r0 + tx] = (bf16)t[tx][ty + j * 8];
}

__global__ __launch_bounds__(256) void cvt_to_bf16(const float* __restrict__ in, bf16* __restrict__ out, long n)
{
    const long i = ((long)blockIdx.x * 256 + threadIdx.x) * 4;
    if (i >= n) return;
    float4 f = *(const float4*)(in + i);
    bf16x4 o; o[0] = (bf16)f.x; o[1] = (bf16)f.y; o[2] = (bf16)f.z; o[3] = (bf16)f.w;
    *(bf16x4*)(out + i) = o;
}

__global__ __launch_bounds__(256) void bcast_slots(const float* __restrict__ seed, float* __restrict__ slots)
{
    const int i = blockIdx.x * 256 + threadIdx.x;
    slots[i] = seed[i & 65535];
}

extern "C" void kernel_launch(void* const* d_in, const int* in_sizes, int n_in,
                              void* d_out, int out_size, void* d_ws, size_t ws_size,
                              hipStream_t stream) {
    const float* inputs     = (const float*)d_in[0];
    const float* W_in       = (const float*)d_in[1];
    const float* b_in       = (const float*)d_in[2];
    const float* slots_seed = (const float*)d_in[3];
    const float* ln_in_g    = (const float*)d_in[4];
    const float* ln_in_b    = (const float*)d_in[5];
    const float* ln_sl_g    = (const float*)d_in[6];
    const float* ln_sl_b    = (const float*)d_in[7];
    const float* ln_mlp_g   = (const float*)d_in[8];
    const float* ln_mlp_b   = (const float*)d_in[9];
    const float* Wq         = (const float*)d_in[10];
    const float* Wk         = (const float*)d_in[11];
    const float* Wv         = (const float*)d_in[12];
    const float* W1         = (const float*)d_in[13];
    const float* b1         = (const float*)d_in[14];
    const float* W2         = (const float*)d_in[15];
    const float* b2         = (const float*)d_in[16];

    char* ws = (char*)d_ws;
    const long MB = 1 << 20;
    bf16* WT_IN = (bf16*)(ws + 0 * MB);     // [1024][1024]
    bf16* WQT   = (bf16*)(ws + 2 * MB);
    bf16* WKT   = (bf16*)(ws + 4 * MB);
    bf16* WVT   = (bf16*)(ws + 6 * MB);
    bf16* W1T   = (bf16*)(ws + 8 * MB);     // [2048][1024]
    bf16* W2T   = (bf16*)(ws + 12 * MB);    // [1024][2048]
    float* SLOTS = (float*)(ws + 16 * MB);  // [512][1024] f32 (slots_ln)
    bf16* SLN   = (bf16*)(ws + 18 * MB);    // [512][1024] bf16 (slots_ln, then h)
    bf16* Q     = (bf16*)(ws + 19 * MB);    // [512][1024]
    float* UPDP = (float*)(ws + 20 * MB);   // [4][512][1024] f32 partials (8MB)
    float* P2   = UPDP;                     // [2][512][1024] f32 partials (alias ok: disjoint lifetime)
    bf16* ATTN  = (bf16*)(ws + 28 * MB);    // [8][64][4096]
    bf16* MLP1  = (bf16*)(ws + 32 * MB);    // [512][2048]
    bf16* X     = (bf16*)(ws + 36 * MB);    // [32768][1024]
    bf16* INP_BF = (bf16*)(ws + 100 * MB);  // [32768][1024] (K aliases after use)
    bf16* K_BF  = INP_BF;
    bf16* XPRE  = (bf16*)(ws + 164 * MB);   // [32768][1024] (vT aliases after use)
    bf16* VT    = XPRE;                     // [8][1024][4096]

    dim3 blk(256);
    dim3 tblk(32, 8);

    transpose_w<<<dim3(32, 32), tblk, 0, stream>>>(W_in, WT_IN, 1024, 1024);
    transpose_w<<<dim3(32, 32), tblk, 0, stream>>>(Wq,   WQT,   1024, 1024);
    transpose_w<<<dim3(32, 32), tblk, 0, stream>>>(Wk,   WKT,   1024, 1024);
    transpose_w<<<dim3(32, 32), tblk, 0, stream>>>(Wv,   WVT,   1024, 1024);
    transpose_w<<<dim3(64, 32), tblk, 0, stream>>>(W1,   W1T,   1024, 2048);
    transpose_w<<<dim3(32, 64), tblk, 0, stream>>>(W2,   W2T,   2048, 1024);

    cvt_to_bf16<<<32768, blk, 0, stream>>>(inputs, INP_BF, (long)32768 * 1024);
    bcast_slots<<<2048, blk, 0, stream>>>(slots_seed, SLOTS);

    // xpre = inputs @ W_in + b_in  (bf16). grid 8x256, XCD swizzle x-inner (A-panel reuse)
    gemm_bt<128, 128, 2, 2, EPI_BIAS_BF16, 1, 1><<<2048, blk, 0, stream>>>(
        INP_BF, WT_IN, XPRE, b_in, 1024, 1024, 0, 0, 0, 1.f, 8, 256, 0);
    // x = LN(xpre)
    ln_rows<1, false, bf16, false><<<32768, blk, 0, stream>>>(XPRE, X, nullptr, ln_in_g, ln_in_b, nullptr, nullptr, 0);
    // k = x @ Wk  (bf16)
    gemm_bt<128, 128, 2, 2, EPI_BF16, 1, 1><<<2048, blk, 0, stream>>>(
        X, WKT, K_BF, nullptr, 1024, 1024, 0, 0, 0, 1.f, 8, 256, 0);
    // vT_b = Wv^T @ x_b^T  -> [8][1024][4096], XCD swizzle y-inner (X-tile reuse)
    gemm_bt<128, 128, 2, 2, EPI_BF16, 1, 2><<<2048, blk, 0, stream>>>(
        WVT, X, VT, nullptr, 4096, 1024, 0, (long)4096 * 1024, (long)1024 * 4096, 1.f, 32, 8, 0);

    for (int it = 0; it < 3; ++it) {
        if (it == 0) {
            // slots_ln = LN(seed slots); keep f32 in SLOTS (in-place) + bf16 in SLN
            ln_rows<1, false, float, true><<<512, blk, 0, stream>>>(
                SLOTS, SLN, SLOTS, ln_sl_g, ln_sl_b, nullptr, nullptr, 0);
        } else {
            // slots = p0+p1+b2+slots_ln_prev ; slots_ln = LN(slots)
            ln_rows<2, true, float, true><<<512, blk, 0, stream>>>(
                P2, SLN, SLOTS, ln_sl_g, ln_sl_b, b2, SLOTS, 524288);
        }
        // q = slots_ln @ Wq * D^-0.5  (bf16)
        gemm_bt<128, 128, 2, 2, EPI_SCALE_BF16, 1, 0><<<32, blk, 0, stream>>>(
            SLN, WQT, Q, nullptr, 1024, 1024, 0, 0, 0, 0.03125f, 8, 4, 0);
        // attn = softmax_slots(q @ k^T)  fused
        qk_softmax<<<256, blk, 0, stream>>>(Q, K_BF, ATTN);
        // updates partials = attn @ v  (split-K=4)
        gemm_bt<64, 256, 1, 4, EPI_F32, 4, 0><<<128, blk, 0, stream>>>(
            ATTN, VT, UPDP, nullptr, 1024, 4096,
            (long)KSLOTS * N_, (long)1024 * 4096, (long)KSLOTS * 1024, 1.f, 4, 1, 524288);
        // h = LN(sum partials)
        ln_rows<4, false, float, false><<<512, blk, 0, stream>>>(
            UPDP, SLN, nullptr, ln_mlp_g, ln_mlp_b, nullptr, nullptr, 524288);
        // mlp1 = gelu(h @ W1 + b1)
        gemm_bt<128, 128, 2, 2, EPI_BIAS_GELU_BF16, 1, 0><<<64, blk, 0, stream>>>(
            SLN, W1T, MLP1, b1, 2048, 1024, 0, 0, 0, 1.f, 16, 4, 0);
        // mlp2 partials (split-K=2); bias+residual applied by next LN / finalize
        gemm_bt<128, 128, 2, 2, EPI_F32, 2, 0><<<64, blk, 0, stream>>>(
            MLP1, W2T, P2, nullptr, 1024, 2048, 0, 0, 0, 1.f, 8, 4, 524288);
    }

    finalize<<<512, blk, 0, stream>>>(P2, b2, SLOTS, (float*)d_out);
}

// Round 5
// 872.954 us; speedup vs baseline: 1.5445x; 1.1271x over previous
//
#include <hip/hip_runtime.h>
#include <hip/hip_bf16.h>
#include <math.h>

#define DEV static __device__ __forceinline__

typedef __bf16 bf16;
typedef __bf16 bf16x8 __attribute__((ext_vector_type(8)));
typedef __bf16 bf16x4 __attribute__((ext_vector_type(4)));
typedef float f32x4 __attribute__((ext_vector_type(4)));

#define B_ 8
#define N_ 4096
#define DD 1024
#define KSLOTS 64
#define EPS_ 1e-5f

enum { EPI_F32=0, EPI_BF16=1, EPI_BIAS_BF16=2, EPI_BIAS_GELU_BF16=3, EPI_SCALE_BF16=5 };

typedef __attribute__((address_space(1))) void gvoid;
typedef __attribute__((address_space(3))) void lvoid;

DEV void gload16(const void* g, void* l) {
    __builtin_amdgcn_global_load_lds((gvoid*)g, (lvoid*)l, 16, 0, 0);
}

// C[M,N] = A[M,K] * Bt[N,K]^T ; A,Bt bf16, acc fp32. 256 threads = 4 waves.
// Wave grid WM x WN (WM*WN==4); per-wave frag counts AM x AN of 16x16.
// KSPLIT>1: writes f32 partials at Cv + ks*pStride (EPI must be EPI_F32).
// SWZ: 0 none; 1 = XCD swizzle, x-inner; 2 = XCD swizzle, y-inner.
template<int BM, int BN, int WM, int WN, int EPI, int KSPLIT, int SWZ>
__global__ __launch_bounds__(256) void gemm_bt(
    const bf16* __restrict__ A, const bf16* __restrict__ Bt, void* __restrict__ Cv,
    const float* __restrict__ bias,
    int N, int Kd, long sA, long sB, long sC, float scale,
    int gx, int gy, long pStride)
{
    constexpr int AM = BM / (WM * 16);
    constexpr int AN = BN / (WN * 16);
    static_assert(WM * WN == 4, "waves");

    __shared__ __align__(16) short lA[BM * 32];
    __shared__ __align__(16) short lB[BN * 32];

    int lin = blockIdx.x;
    if (SWZ) {
        int cpx = gridDim.x >> 3;           // grid % 8 == 0 guaranteed by caller
        lin = (lin & 7) * cpx + (lin >> 3);
    }
    int bx, by, bzk;
    if (SWZ == 2) { by = lin % gy; int t = lin / gy; bx = t % gx; bzk = t / gx; }
    else          { bx = lin % gx; int t = lin / gx; by = t % gy; bzk = t / gy; }
    const int b  = bzk / KSPLIT;
    const int ks = bzk % KSPLIT;
    const int kLen = Kd / KSPLIT;
    const int kBeg = ks * kLen;

    const int tid  = threadIdx.x;
    const int lane = tid & 63;
    const int wave = tid >> 6;
    const int wm = wave / WN;
    const int wn = wave % WN;
    const int lr = lane & 15;
    const int lk = lane >> 4;

    const bf16* ga = A  + (long)b * sA + (long)by * BM * Kd;
    const bf16* gb = Bt + (long)b * sB + (long)bx * BN * Kd;

    f32x4 acc[AM][AN] = {};

    for (int k0 = kBeg; k0 < kBeg + kLen; k0 += 32) {
        #pragma unroll
        for (int j = 0; j < BM / 64; ++j) {
            int c = j * 256 + tid;
            gload16(ga + (long)(c >> 2) * Kd + k0 + (c & 3) * 8,
                    lA + (j * 256 + wave * 64) * 8);
        }
        #pragma unroll
        for (int j = 0; j < BN / 64; ++j) {
            int c = j * 256 + tid;
            gload16(gb + (long)(c >> 2) * Kd + k0 + (c & 3) * 8,
                    lB + (j * 256 + wave * 64) * 8);
        }
        __syncthreads();

        bf16x8 af[AM], bfr[AN];
        #pragma unroll
        for (int i = 0; i < AM; ++i)
            af[i] = *(const bf16x8*)&lA[(wm * AM * 16 + i * 16 + lr) * 32 + lk * 8];
        #pragma unroll
        for (int j = 0; j < AN; ++j)
            bfr[j] = *(const bf16x8*)&lB[(wn * AN * 16 + j * 16 + lr) * 32 + lk * 8];

        #pragma unroll
        for (int i = 0; i < AM; ++i)
            #pragma unroll
            for (int j = 0; j < AN; ++j)
                acc[i][j] = __builtin_amdgcn_mfma_f32_16x16x32_bf16(af[i], bfr[j], acc[i][j], 0, 0, 0);
        __syncthreads();
    }

    const int rowb = by * BM + wm * AM * 16;
    const int colb = bx * BN + wn * AN * 16;

    #pragma unroll
    for (int i = 0; i < AM; ++i) {
        #pragma unroll
        for (int j = 0; j < AN; ++j) {
            const int col = colb + j * 16 + lr;
            float bv = 0.f;
            if (EPI == EPI_BIAS_BF16 || EPI == EPI_BIAS_GELU_BF16)
                bv = bias[col];
            #pragma unroll
            for (int r = 0; r < 4; ++r) {
                const int row = rowb + i * 16 + lk * 4 + r;
                float v = acc[i][j][r];
                if (KSPLIT > 1) {
                    float* P = (float*)Cv + (long)ks * pStride;
                    P[(long)b * sC + (long)row * N + col] = v;
                } else {
                    const long off = (long)b * sC + (long)row * N + col;
                    if (EPI == EPI_F32) {
                        ((float*)Cv)[off] = v;
                    } else if (EPI == EPI_BF16) {
                        ((bf16*)Cv)[off] = (bf16)v;
                    } else if (EPI == EPI_BIAS_BF16) {
                        ((bf16*)Cv)[off] = (bf16)(v + bv);
                    } else if (EPI == EPI_SCALE_BF16) {
                        ((bf16*)Cv)[off] = (bf16)(v * scale);
                    } else if (EPI == EPI_BIAS_GELU_BF16) {
                        float t = v + bv;
                        t = 0.5f * t * (1.f + erff(t * 0.70710678118f));
                        ((bf16*)Cv)[off] = (bf16)t;
                    }
                }
            }
        }
    }
}

// Fused logits + column-softmax (over the 64 slots) -> attn bf16.
// BM=64 (all slots), BN=128, WM=1, WN=4. grid = 32 n-tiles * 8 batches.
__global__ __launch_bounds__(256) void qk_softmax(
    const bf16* __restrict__ Q, const bf16* __restrict__ Kb, bf16* __restrict__ attn)
{
    __shared__ __align__(16) short lA[64 * 32];
    __shared__ __align__(16) short lB[128 * 32];

    const int bx = blockIdx.x & 31;
    const int z  = blockIdx.x >> 5;
    const int tid  = threadIdx.x;
    const int lane = tid & 63;
    const int wave = tid >> 6;   // = wn
    const int lr = lane & 15;
    const int lk = lane >> 4;

    const bf16* ga = Q  + (long)z * (KSLOTS * DD);
    const bf16* gb = Kb + (long)z * (N_ * DD) + (long)bx * 128 * DD;

    f32x4 acc[4][2] = {};

    for (int k0 = 0; k0 < DD; k0 += 32) {
        {
            int c = tid;
            gload16(ga + (long)(c >> 2) * DD + k0 + (c & 3) * 8, lA + (wave * 64) * 8);
        }
        #pragma unroll
        for (int j = 0; j < 2; ++j) {
            int c = j * 256 + tid;
            gload16(gb + (long)(c >> 2) * DD + k0 + (c & 3) * 8,
                    lB + (j * 256 + wave * 64) * 8);
        }
        __syncthreads();

        bf16x8 af[4], bfr[2];
        #pragma unroll
        for (int i = 0; i < 4; ++i)
            af[i] = *(const bf16x8*)&lA[(i * 16 + lr) * 32 + lk * 8];
        #pragma unroll
        for (int j = 0; j < 2; ++j)
            bfr[j] = *(const bf16x8*)&lB[(wave * 32 + j * 16 + lr) * 32 + lk * 8];

        #pragma unroll
        for (int i = 0; i < 4; ++i)
            #pragma unroll
            for (int j = 0; j < 2; ++j)
                acc[i][j] = __builtin_amdgcn_mfma_f32_16x16x32_bf16(af[i], bfr[j], acc[i][j], 0, 0, 0);
        __syncthreads();
    }

    bf16* ob = attn + (long)z * (KSLOTS * N_);
    #pragma unroll
    for (int j = 0; j < 2; ++j) {
        const int col = bx * 128 + wave * 32 + j * 16 + lr;
        float m = -1e30f;
        #pragma unroll
        for (int i = 0; i < 4; ++i)
            #pragma unroll
            for (int r = 0; r < 4; ++r) m = fmaxf(m, acc[i][j][r]);
        m = fmaxf(m, __shfl_xor(m, 16));
        m = fmaxf(m, __shfl_xor(m, 32));
        float e[4][4], s = 0.f;
        #pragma unroll
        for (int i = 0; i < 4; ++i)
            #pragma unroll
            for (int r = 0; r < 4; ++r) { e[i][r] = __expf(acc[i][j][r] - m); s += e[i][r]; }
        s += __shfl_xor(s, 16);
        s += __shfl_xor(s, 32);
        const float inv = 1.f / s;
        #pragma unroll
        for (int i = 0; i < 4; ++i)
            #pragma unroll
            for (int r = 0; r < 4; ++r)
                ob[(long)(i * 16 + lk * 4 + r) * N_ + col] = (bf16)(e[i][r] * inv);
    }
}

// LayerNorm over rows of length 1024.
// NPART>1: input = NPART f32 partials (summed). ADD_BR: += bias[col] + res[row] first.
// WRITE_F32: also write f32 result to outf (may alias res).
template<int NPART, bool ADD_BR, typename TIN, bool WRITE_F32>
__global__ __launch_bounds__(256) void ln_rows(const TIN* __restrict__ in, bf16* __restrict__ out,
                                               float* outf, const float* __restrict__ g,
                                               const float* __restrict__ b,
                                               const float* __restrict__ bias, const float* res,
                                               long pStride)
{
    const int row = blockIdx.x;
    const int tid = threadIdx.x;
    const long base = (long)row * 1024 + tid * 4;
    float x[4];
    if constexpr (sizeof(TIN) == 2) {
        bf16x4 v = *(const bf16x4*)(in + base);
        #pragma unroll
        for (int i = 0; i < 4; ++i) x[i] = (float)v[i];
    } else {
        float4 v = *(const float4*)((const float*)in + base);
        x[0] = v.x; x[1] = v.y; x[2] = v.z; x[3] = v.w;
        #pragma unroll
        for (int p = 1; p < NPART; ++p) {
            float4 w = *(const float4*)((const float*)in + p * pStride + base);
            x[0] += w.x; x[1] += w.y; x[2] += w.z; x[3] += w.w;
        }
    }
    const int c0 = tid * 4;
    if constexpr (ADD_BR) {
        float4 rv = *(const float4*)(res + base);
        x[0] += bias[c0 + 0] + rv.x; x[1] += bias[c0 + 1] + rv.y;
        x[2] += bias[c0 + 2] + rv.z; x[3] += bias[c0 + 3] + rv.w;
    }
    float s = 0.f, s2 = 0.f;
    #pragma unroll
    for (int i = 0; i < 4; ++i) { s += x[i]; s2 += x[i] * x[i]; }
    #pragma unroll
    for (int o = 32; o; o >>= 1) { s += __shfl_down(s, o); s2 += __shfl_down(s2, o); }
    __shared__ float red[2][4];
    const int lane = tid & 63, wv = tid >> 6;
    if (!lane) { red[0][wv] = s; red[1][wv] = s2; }
    __syncthreads();
    s  = red[0][0] + red[0][1] + red[0][2] + red[0][3];
    s2 = red[1][0] + red[1][1] + red[1][2] + red[1][3];
    const float mu = s * (1.f / 1024.f);
    const float var = s2 * (1.f / 1024.f) - mu * mu;
    const float rstd = rsqrtf(var + EPS_);
    bf16x4 o;
    float of[4];
    #pragma unroll
    for (int i = 0; i < 4; ++i) {
        float y = (x[i] - mu) * rstd * g[c0 + i] + b[c0 + i];
        o[i] = (bf16)y; of[i] = y;
    }
    *(bf16x4*)(out + base) = o;
    if constexpr (WRITE_F32) {
        float4 v4; v4.x = of[0]; v4.y = of[1]; v4.z = of[2]; v4.w = of[3];
        *(float4*)(outf + base) = v4;
    }
}

// final slots = p0 + p1 + b2 + slots_ln  -> d_out (f32)
__global__ __launch_bounds__(256) void finalize(const float* __restrict__ P, const float* __restrict__ bias,
                                                const float* __restrict__ res, float* __restrict__ out)
{
    const int row = blockIdx.x;
    const int tid = threadIdx.x;
    const long base = (long)row * 1024 + tid * 4;
    float4 a = *(const float4*)(P + base);
    float4 c = *(const float4*)(P + 524288 + base);
    float4 rv = *(const float4*)(res + base);
    const int c0 = tid * 4;
    float4 o;
    o.x = a.x + c.x + bias[c0 + 0] + rv.x;
    o.y = a.y + c.y + bias[c0 + 1] + rv.y;
    o.z = a.z + c.z + bias[c0 + 2] + rv.z;
    o.w = a.w + c.w + bias[c0 + 3] + rv.w;
    *(float4*)(out + base) = o;
}

// out[c][r] = (bf16) in[r][c]; in is [R][C] fp32.
__global__ __launch_bounds__(256) void transpose_w(const float* __restrict__ in, bf16* __restrict__ out,
                                                   int R, int C)
{
    __shared__ float t[32][33];
    const int tx = threadIdx.x, ty = threadIdx.y;
    const int c0 = blockIdx.x * 32, r0 = blockIdx.y * 32;
    #pragma unroll
    for (int j = 0; j < 4; ++j)
        t[ty + j * 8][tx] = in[(long)(r0 + ty + j * 8) * C + c0 + tx];
    __syncthreads();
    #pragma unroll
    for (int j = 0; j < 4; ++j)
        out[(long)(c0 + ty + j * 8) * R + r0 + tx] = (bf16)t[tx][ty + j * 8];
}

__global__ __launch_bounds__(256) void cvt_to_bf16(const float* __restrict__ in, bf16* __restrict__ out, long n)
{
    const long i = ((long)blockIdx.x * 256 + threadIdx.x) * 4;
    if (i >= n) return;
    float4 f = *(const float4*)(in + i);
    bf16x4 o; o[0] = (bf16)f.x; o[1] = (bf16)f.y; o[2] = (bf16)f.z; o[3] = (bf16)f.w;
    *(bf16x4*)(out + i) = o;
}

__global__ __launch_bounds__(256) void bcast_slots(const float* __restrict__ seed, float* __restrict__ slots)
{
    const int i = blockIdx.x * 256 + threadIdx.x;
    slots[i] = seed[i & 65535];
}

extern "C" void kernel_launch(void* const* d_in, const int* in_sizes, int n_in,
                              void* d_out, int out_size, void* d_ws, size_t ws_size,
                              hipStream_t stream) {
    const float* inputs     = (const float*)d_in[0];
    const float* W_in       = (const float*)d_in[1];
    const float* b_in       = (const float*)d_in[2];
    const float* slots_seed = (const float*)d_in[3];
    const float* ln_in_g    = (const float*)d_in[4];
    const float* ln_in_b    = (const float*)d_in[5];
    const float* ln_sl_g    = (const float*)d_in[6];
    const float* ln_sl_b    = (const float*)d_in[7];
    const float* ln_mlp_g   = (const float*)d_in[8];
    const float* ln_mlp_b   = (const float*)d_in[9];
    const float* Wq         = (const float*)d_in[10];
    const float* Wk         = (const float*)d_in[11];
    const float* Wv         = (const float*)d_in[12];
    const float* W1         = (const float*)d_in[13];
    const float* b1         = (const float*)d_in[14];
    const float* W2         = (const float*)d_in[15];
    const float* b2         = (const float*)d_in[16];

    char* ws = (char*)d_ws;
    const long MB = 1 << 20;
    bf16* WT_IN = (bf16*)(ws + 0 * MB);     // [1024][1024]
    bf16* WQT   = (bf16*)(ws + 2 * MB);
    bf16* WKT   = (bf16*)(ws + 4 * MB);
    bf16* WVT   = (bf16*)(ws + 6 * MB);
    bf16* W1T   = (bf16*)(ws + 8 * MB);     // [2048][1024]
    bf16* W2T   = (bf16*)(ws + 12 * MB);    // [1024][2048]
    float* SLOTS = (float*)(ws + 16 * MB);  // [512][1024] f32 (slots_ln)
    bf16* SLN   = (bf16*)(ws + 18 * MB);    // [512][1024] bf16 (slots_ln, then h)
    bf16* Q     = (bf16*)(ws + 19 * MB);    // [512][1024]
    float* UPDP = (float*)(ws + 20 * MB);   // [4][512][1024] f32 partials (8MB)
    float* P2   = UPDP;                     // [2][512][1024] f32 partials (alias ok: disjoint lifetime)
    bf16* ATTN  = (bf16*)(ws + 28 * MB);    // [8][64][4096]
    bf16* MLP1  = (bf16*)(ws + 32 * MB);    // [512][2048]
    bf16* X     = (bf16*)(ws + 36 * MB);    // [32768][1024]
    bf16* INP_BF = (bf16*)(ws + 100 * MB);  // [32768][1024] (K aliases after use)
    bf16* K_BF  = INP_BF;
    bf16* XPRE  = (bf16*)(ws + 164 * MB);   // [32768][1024] (vT aliases after use)
    bf16* VT    = XPRE;                     // [8][1024][4096]

    dim3 blk(256);
    dim3 tblk(32, 8);

    transpose_w<<<dim3(32, 32), tblk, 0, stream>>>(W_in, WT_IN, 1024, 1024);
    transpose_w<<<dim3(32, 32), tblk, 0, stream>>>(Wq,   WQT,   1024, 1024);
    transpose_w<<<dim3(32, 32), tblk, 0, stream>>>(Wk,   WKT,   1024, 1024);
    transpose_w<<<dim3(32, 32), tblk, 0, stream>>>(Wv,   WVT,   1024, 1024);
    transpose_w<<<dim3(64, 32), tblk, 0, stream>>>(W1,   W1T,   1024, 2048);
    transpose_w<<<dim3(32, 64), tblk, 0, stream>>>(W2,   W2T,   2048, 1024);

    cvt_to_bf16<<<32768, blk, 0, stream>>>(inputs, INP_BF, (long)32768 * 1024);
    bcast_slots<<<2048, blk, 0, stream>>>(slots_seed, SLOTS);

    // xpre = inputs @ W_in + b_in  (bf16). grid 8x256, XCD swizzle x-inner (A-panel reuse)
    gemm_bt<128, 128, 2, 2, EPI_BIAS_BF16, 1, 1><<<2048, blk, 0, stream>>>(
        INP_BF, WT_IN, XPRE, b_in, 1024, 1024, 0, 0, 0, 1.f, 8, 256, 0);
    // x = LN(xpre)
    ln_rows<1, false, bf16, false><<<32768, blk, 0, stream>>>(XPRE, X, nullptr, ln_in_g, ln_in_b, nullptr, nullptr, 0);
    // k = x @ Wk  (bf16)
    gemm_bt<128, 128, 2, 2, EPI_BF16, 1, 1><<<2048, blk, 0, stream>>>(
        X, WKT, K_BF, nullptr, 1024, 1024, 0, 0, 0, 1.f, 8, 256, 0);
    // vT_b = Wv^T @ x_b^T  -> [8][1024][4096], XCD swizzle y-inner (X-tile reuse)
    gemm_bt<128, 128, 2, 2, EPI_BF16, 1, 2><<<2048, blk, 0, stream>>>(
        WVT, X, VT, nullptr, 4096, 1024, 0, (long)4096 * 1024, (long)1024 * 4096, 1.f, 32, 8, 0);

    for (int it = 0; it < 3; ++it) {
        if (it == 0) {
            // slots_ln = LN(seed slots); keep f32 in SLOTS (in-place) + bf16 in SLN
            ln_rows<1, false, float, true><<<512, blk, 0, stream>>>(
                SLOTS, SLN, SLOTS, ln_sl_g, ln_sl_b, nullptr, nullptr, 0);
        } else {
            // slots = p0+p1+b2+slots_ln_prev ; slots_ln = LN(slots)
            ln_rows<2, true, float, true><<<512, blk, 0, stream>>>(
                P2, SLN, SLOTS, ln_sl_g, ln_sl_b, b2, SLOTS, 524288);
        }
        // q = slots_ln @ Wq * D^-0.5  (bf16). 64x64 tiles -> 128 blocks
        gemm_bt<64, 64, 2, 2, EPI_SCALE_BF16, 1, 0><<<128, blk, 0, stream>>>(
            SLN, WQT, Q, nullptr, 1024, 1024, 0, 0, 0, 0.03125f, 16, 8, 0);
        // attn = softmax_slots(q @ k^T)  fused
        qk_softmax<<<256, blk, 0, stream>>>(Q, K_BF, ATTN);
        // updates partials = attn @ v  (64x128 tiles, split-K=4 -> 256 blocks)
        gemm_bt<64, 128, 2, 2, EPI_F32, 4, 0><<<256, blk, 0, stream>>>(
            ATTN, VT, UPDP, nullptr, 1024, 4096,
            (long)KSLOTS * N_, (long)1024 * 4096, (long)KSLOTS * 1024, 1.f, 8, 1, 524288);
        // h = LN(sum partials)
        ln_rows<4, false, float, false><<<512, blk, 0, stream>>>(
            UPDP, SLN, nullptr, ln_mlp_g, ln_mlp_b, nullptr, nullptr, 524288);
        // mlp1 = gelu(h @ W1 + b1)  (64x128 tiles -> 128 blocks)
        gemm_bt<64, 128, 2, 2, EPI_BIAS_GELU_BF16, 1, 0><<<128, blk, 0, stream>>>(
            SLN, W1T, MLP1, b1, 2048, 1024, 0, 0, 0, 1.f, 16, 8, 0);
        // mlp2 partials (64x128 tiles, split-K=2 -> 128 blocks)
        gemm_bt<64, 128, 2, 2, EPI_F32, 2, 0><<<128, blk, 0, stream>>>(
            MLP1, W2T, P2, nullptr, 1024, 2048, 0, 0, 0, 1.f, 8, 8, 524288);
    }

    finalize<<<512, blk, 0, stream>>>(P2, b2, SLOTS, (float*)d_out);
}